// Round 11
// baseline (308.637 us; speedup 1.0000x reference)
//
#include <hip/hip_runtime.h>
#include <hip/hip_bf16.h>

typedef __attribute__((ext_vector_type(4))) float f32x4;
typedef __attribute__((ext_vector_type(8))) short bf16x8;

#define NR 12288
#define HD 256
#define TAU 0.5f
#define NU 24576              // unified rows (n1;n2)
#define NTT 192               // 128-row tiles per dim of unified matrix
#define NSUB 384              // partial-sum slots (fp32) — fully covered, no memset needed
#define NBLK (NTT * (NTT + 1) / 2)   // 18528 = 8 * 2316
#define LAM 1.69864368f       // sqrt(log2(e)/TAU); gram acc = sim*log2e/tau directly

__device__ __forceinline__ unsigned short f2bf(float f) {
    unsigned int x = __builtin_bit_cast(unsigned int, f);
    x += 0x7fffu + ((x >> 16) & 1u);
    return (unsigned short)(x >> 16);
}

// manual OCP e4m3fn cast, RNE in normal range, step-round in denormal range
__device__ __forceinline__ unsigned char f2e4m3(float f) {
    unsigned int u = __builtin_bit_cast(unsigned int, f);
    unsigned int s = (u >> 24) & 0x80u;
    float af = fabsf(f);
    if (af >= 464.f) return (unsigned char)(s | 0x7Eu);      // saturate to 448
    if (af < 0.015625f) {                                    // denormal: step 2^-9
        unsigned int q = (unsigned int)(af * 512.f + 0.5f);
        return (unsigned char)(s | q);
    }
    int e = (int)((u >> 23) & 0xffu) - 127;
    unsigned int mant = u & 0x7fffffu;
    unsigned int val = (unsigned int)((e + 7) << 3) | (mant >> 20);
    unsigned int rem = mant & 0xfffffu;
    val += (rem > 0x80000u) || (rem == 0x80000u && (val & 1u));
    return (unsigned char)(s | val);
}

// sum over each 16-lane group via 4 DPP adds — pure VALU, zero LDS-pipe traffic.
__device__ __forceinline__ float row16_sum(float x) {
    int v;
    v = __builtin_amdgcn_update_dpp(0, __builtin_bit_cast(int, x), 0xB1, 0xF, 0xF, true);
    x += __builtin_bit_cast(float, v);
    v = __builtin_amdgcn_update_dpp(0, __builtin_bit_cast(int, x), 0x4E, 0xF, 0xF, true);
    x += __builtin_bit_cast(float, v);
    v = __builtin_amdgcn_update_dpp(0, __builtin_bit_cast(int, x), 0x141, 0xF, 0xF, true);
    x += __builtin_bit_cast(float, v);
    v = __builtin_amdgcn_update_dpp(0, __builtin_bit_cast(int, x), 0x140, 0xF, 0xF, true);
    x += __builtin_bit_cast(float, v);
    return x;
}

// load 8 consecutive f32 and round-to-nearest-even pack into bf16x8
__device__ __forceinline__ bf16x8 cvt8(const float* __restrict__ p) {
    float4 a = *(const float4*)p;
    float4 b = *(const float4*)(p + 4);
    union { unsigned int i[4]; bf16x8 v; } u;
    u.i[0] = ((unsigned int)f2bf(a.y) << 16) | f2bf(a.x);
    u.i[1] = ((unsigned int)f2bf(a.w) << 16) | f2bf(a.z);
    u.i[2] = ((unsigned int)f2bf(b.y) << 16) | f2bf(b.x);
    u.i[3] = ((unsigned int)f2bf(b.w) << 16) | f2bf(b.z);
    return u.v;
}

// ---------- W[k][n] f32 -> Wt[n][k] bf16 ----------
__global__ __launch_bounds__(256) void transpose_cast_kernel(const float* __restrict__ W,
                                                             unsigned short* __restrict__ Wt) {
    int n = blockIdx.x;
    int k = threadIdx.x;
    Wt[n * HD + k] = f2bf(W[k * HD + n]);
}

// ---------- mega-fused projection: z{1,2} -> GEMM1+ELU -> GEMM2+bias -> norm/dot -> fp8 nU + dvec ----------
// 192 blocks x 256 threads (4 waves; wave owns 64 rows x 64 cols, col0 = wave*64).
// LDS t tile [64 rows][512 B] bf16, chunk-XOR swizzle: data chunk c of row r stored at
// chunk c ^ (r&15). BUGFIX vs R10: write chunk includes the wave's column-stripe offset
// wave*8 (= col0/8) — omitting it made all 4 waves clobber chunks 0..7.
__global__ __launch_bounds__(256, 1) void fused_proj_kernel(const float* __restrict__ z1,
                                                            const float* __restrict__ z2,
                                                            const unsigned short* __restrict__ W1t,
                                                            const unsigned short* __restrict__ W2t,
                                                            const float* __restrict__ b1,
                                                            const float* __restrict__ b2,
                                                            unsigned char* __restrict__ nU,
                                                            float* __restrict__ dvec) {
    __shared__ __align__(16) unsigned char tbuf[64 * 512];   // 32KB bf16 tile
    __shared__ float red1[4][64];
    __shared__ float red2[4][64];
    __shared__ float redd[4][64];
    __shared__ float iaA[64], ibA[64];

    const int t = threadIdx.x;
    const int lane = t & 63;
    const int wave = t >> 6;
    const int lr = lane & 15, lk = lane >> 4;
    const int row0 = blockIdx.x * 64;
    const int col0 = wave * 64;

    float b1v[4], b2v[4];
#pragma unroll
    for (int n = 0; n < 4; ++n) {
        b1v[n] = b1[col0 + n * 16 + lr];
        b2v[n] = b2[col0 + n * 16 + lr];
    }

    f32x4 h1[4][4], h2[4][4];

    // two phases: ph=0 -> z1/h1, ph=1 -> z2/h2
#pragma unroll 1
    for (int ph = 0; ph < 2; ++ph) {
        const float* zsrc = ph ? z2 : z1;
        // ---- GEMM1: z @ W1t^T ----
        f32x4 a1[4][4] = {};
#pragma unroll
        for (int ks = 0; ks < 8; ++ks) {
            bf16x8 af[4], bfr[4];
#pragma unroll
            for (int m = 0; m < 4; ++m)
                af[m] = cvt8(zsrc + (size_t)(row0 + m * 16 + lr) * HD + ks * 32 + lk * 8);
#pragma unroll
            for (int n = 0; n < 4; ++n)
                bfr[n] = *(const bf16x8*)(W1t + (size_t)(col0 + n * 16 + lr) * HD + ks * 32 + lk * 8);
#pragma unroll
            for (int m = 0; m < 4; ++m)
#pragma unroll
                for (int n = 0; n < 4; ++n)
                    a1[m][n] = __builtin_amdgcn_mfma_f32_16x16x32_bf16(af[m], bfr[n], a1[m][n], 0, 0, 0);
        }
        // ---- ELU + bf16 -> swizzled LDS tile ----
#pragma unroll
        for (int m = 0; m < 4; ++m)
#pragma unroll
            for (int n = 0; n < 4; ++n)
#pragma unroll
                for (int r = 0; r < 4; ++r) {
                    float v = a1[m][n][r] + b1v[n];
                    v = v > 0.f ? v : expm1f(v);
                    const int row_l = m * 16 + lk * 4 + r;
                    const int chunk = (wave * 8 + n * 2 + (lr >> 3)) ^ (row_l & 15);  // FIX: +wave*8
                    *(unsigned short*)(tbuf + row_l * 512 + chunk * 16 + (lr & 7) * 2) = f2bf(v);
                }
        __syncthreads();
        // ---- GEMM2: t @ W2t^T ----
        f32x4 a2[4][4] = {};
#pragma unroll
        for (int ks = 0; ks < 8; ++ks) {
            bf16x8 af[4], bfr[4];
#pragma unroll
            for (int m = 0; m < 4; ++m)
                af[m] = *(const bf16x8*)(tbuf + (m * 16 + lr) * 512 + (((ks * 4 + lk) ^ lr) * 16));
#pragma unroll
            for (int n = 0; n < 4; ++n)
                bfr[n] = *(const bf16x8*)(W2t + (size_t)(col0 + n * 16 + lr) * HD + ks * 32 + lk * 8);
#pragma unroll
            for (int m = 0; m < 4; ++m)
#pragma unroll
                for (int n = 0; n < 4; ++n)
                    a2[m][n] = __builtin_amdgcn_mfma_f32_16x16x32_bf16(af[m], bfr[n], a2[m][n], 0, 0, 0);
        }
#pragma unroll
        for (int m = 0; m < 4; ++m)
#pragma unroll
            for (int n = 0; n < 4; ++n)
#pragma unroll
                for (int r = 0; r < 4; ++r) {
                    float v = a2[m][n][r] + b2v[n];
                    if (ph == 0) h1[m][n][r] = v; else h2[m][n][r] = v;
                }
        // ---- per-row partial reductions over this wave's 64 cols ----
#pragma unroll
        for (int m = 0; m < 4; ++m)
#pragma unroll
            for (int r = 0; r < 4; ++r) {
                const int row_l = m * 16 + lk * 4 + r;
                if (ph == 0) {
                    float ss = h1[m][0][r] * h1[m][0][r] + h1[m][1][r] * h1[m][1][r] +
                               h1[m][2][r] * h1[m][2][r] + h1[m][3][r] * h1[m][3][r];
                    ss = row16_sum(ss);
                    if (lr == 0) red1[wave][row_l] = ss;
                } else {
                    float ss = h2[m][0][r] * h2[m][0][r] + h2[m][1][r] * h2[m][1][r] +
                               h2[m][2][r] * h2[m][2][r] + h2[m][3][r] * h2[m][3][r];
                    float dd = h1[m][0][r] * h2[m][0][r] + h1[m][1][r] * h2[m][1][r] +
                               h1[m][2][r] * h2[m][2][r] + h1[m][3][r] * h2[m][3][r];
                    ss = row16_sum(ss);
                    dd = row16_sum(dd);
                    if (lr == 0) { red2[wave][row_l] = ss; redd[wave][row_l] = dd; }
                }
            }
        __syncthreads();   // red complete; tile reads complete (safe to overwrite next phase)
    }

    // ---- finalize per-row norms + dvec, broadcast scaled inverse norms ----
    if (t < 64) {
        float s1 = red1[0][t] + red1[1][t] + red1[2][t] + red1[3][t];
        float s2 = red2[0][t] + red2[1][t] + red2[2][t] + red2[3][t];
        float dd = redd[0][t] + redd[1][t] + redd[2][t] + redd[3][t];
        float na = sqrtf(s1); na = na > 1e-12f ? na : 1e-12f;
        float nb = sqrtf(s2); nb = nb > 1e-12f ? nb : 1e-12f;
        float ia = 1.f / na, ib = 1.f / nb;
        dvec[row0 + t] = dd * ia * ib * (1.f / TAU);
        iaA[t] = ia * LAM;
        ibA[t] = ib * LAM;
    }
    __syncthreads();

    // ---- quantize to fp8 with bit3 half-swap layout ----
    unsigned char* n1p = nU;
    unsigned char* n2p = nU + (size_t)NR * HD;
#pragma unroll
    for (int m = 0; m < 4; ++m)
#pragma unroll
        for (int r = 0; r < 4; ++r) {
            const int row_l = m * 16 + lk * 4 + r;
            const float iav = iaA[row_l];
            const float ibv = ibA[row_l];
            const int sw8 = ((row_l >> 3) & 1) << 3;
            const size_t rb = (size_t)(row0 + row_l) * HD;
#pragma unroll
            for (int n = 0; n < 4; ++n) {
                const int col = (col0 + n * 16 + lr) ^ sw8;
                n1p[rb + col] = f2e4m3(h1[m][n][r] * iav);
                n2p[rb + col] = f2e4m3(h2[m][n][r] * ibv);
            }
        }
}

// ---------- unified symmetric Gram (fp8): upper-tri 128x128 tiles of exp2(M@M^T) ----------
// Inputs pre-scaled by LAM so acc = sim*log2e/tau directly (no epilogue mul).
// Best config (R9): 4 waves 64x64, 64 KiB LDS, 2 blocks/CU, barrier-free K-loop,
// chunk-XOR + half-swap conflict-free b64 reads, DPP rowsum. No memset needed:
// panel p gets rowsum slots [2p,384) and colsum slots [0,2p) — exact cover of [0,384).
__global__ __launch_bounds__(256, 2) void gram_kernel(const unsigned char* __restrict__ nU8,
                                                      float* __restrict__ RPART) {
    __shared__ __align__(16) unsigned char lA[128 * 256];  // 32KB
    __shared__ __align__(16) unsigned char lB[128 * 256];  // 32KB

    const int bid = blockIdx.x;
    const int t0 = (bid & 7) * (NBLK / 8) + (bid >> 3);
    int i = (int)((385.f - sqrtf((float)(385 * 385 - 8 * t0))) * 0.5f);
    if (i < 0) i = 0;
    if (i > NTT - 1) i = NTT - 1;
    while (i > 0 && i * NTT - i * (i - 1) / 2 > t0) --i;
    while ((i + 1) * NTT - (i + 1) * i / 2 <= t0) ++i;
    const int j = i + (t0 - (i * NTT - i * (i - 1) / 2));
    const bool diag = (i == j);

    const unsigned char* X = nU8 + (size_t)i * 128 * HD;
    const unsigned char* Y = nU8 + (size_t)j * 128 * HD;

    const int t = threadIdx.x;
    const int lane = t & 63;
    const int wave = t >> 6;
    const int wr = wave >> 1, wc = wave & 1;      // 2x2 wave grid; wave tile 64x64
    const int lr = lane & 15, lk = lane >> 4;

    {
        const int rbase = t >> 4;                              // 0..15
        const int schunk = (t & 15) ^ rbase;                   // pre-swizzled source slot
        const unsigned char* gx = X + rbase * 256 + schunk * 16;
        const unsigned char* gy = Y + rbase * 256 + schunk * 16;
#pragma unroll
        for (int c = 0; c < 8; ++c) {
            __builtin_amdgcn_global_load_lds(
                (const __attribute__((address_space(1))) unsigned int*)(gx + c * 4096),
                (__attribute__((address_space(3))) unsigned int*)(&lA[c * 4096 + t * 16]),
                16, 0, 0);
        }
        if (!diag) {
#pragma unroll
            for (int c = 0; c < 8; ++c) {
                __builtin_amdgcn_global_load_lds(
                    (const __attribute__((address_space(1))) unsigned int*)(gy + c * 4096),
                    (__attribute__((address_space(3))) unsigned int*)(&lB[c * 4096 + t * 16]),
                    16, 0, 0);
            }
        }
    }
    __syncthreads();   // the ONLY barrier in this kernel

    f32x4 acc[4][4] = {};
    const int hswap = (lr >> 3) & 1;
    const unsigned char* sA = lA + (size_t)(wr * 64 + lr) * 256 + ((lk & 1) ^ hswap) * 8;
    const unsigned char* sBb = (diag ? lA : lB);
    const unsigned char* sB = sBb + (size_t)(wc * 64 + lr) * 256 + ((lk & 1) ^ hswap) * 8;
#pragma unroll
    for (int ks = 0; ks < 8; ++ks) {
        const int chnk = ((2 * ks + (lk >> 1)) ^ lr) * 16;
        long af[4], bfr[4];
#pragma unroll
        for (int m = 0; m < 4; ++m)
            af[m] = *(const long*)(sA + m * 16 * 256 + chnk);
#pragma unroll
        for (int n = 0; n < 4; ++n)
            bfr[n] = *(const long*)(sB + n * 16 * 256 + chnk);
#pragma unroll
        for (int m = 0; m < 4; ++m)
#pragma unroll
            for (int n = 0; n < 4; ++n)
                acc[m][n] = __builtin_amdgcn_mfma_f32_16x16x32_fp8_fp8(af[m], bfr[n], acc[m][n], 0, 0, 0);
    }

#pragma unroll
    for (int m = 0; m < 4; ++m)
#pragma unroll
        for (int n = 0; n < 4; ++n)
#pragma unroll
            for (int r = 0; r < 4; ++r)
                acc[m][n][r] = exp2f(acc[m][n][r]);    // LAM pre-fold: acc already sim*log2e/tau

    // rowsum partials
    {
        float* dst = RPART + (size_t)(2 * j + wc) * NU + i * 128 + wr * 64;
#pragma unroll
        for (int m = 0; m < 4; ++m) {
#pragma unroll
            for (int r = 0; r < 4; ++r) {
                float rs = (acc[m][0][r] + acc[m][1][r]) + (acc[m][2][r] + acc[m][3][r]);
                rs = row16_sum(rs);
                if (lr == 0) dst[m * 16 + lk * 4 + r] = rs;
            }
        }
    }
    // colsum partials (off-diag)
    if (!diag) {
        float* dst = RPART + (size_t)(2 * i + wr) * NU + j * 128 + wc * 64;
#pragma unroll
        for (int n = 0; n < 4; ++n) {
            float cs = 0.f;
#pragma unroll
            for (int m = 0; m < 4; ++m)
#pragma unroll
                for (int r = 0; r < 4; ++r) cs += acc[m][n][r];
            cs += __shfl_xor(cs, 16);
            cs += __shfl_xor(cs, 32);
            if (lk == 0) dst[n * 16 + lr] = cs;
        }
    }
}

// ---------- fused reduce + loss: S terms from RPART, log-loss, block partials ----------
__global__ __launch_bounds__(128) void loss_sum_kernel(const float* __restrict__ RPART,
                                                       const float* __restrict__ dvec,
                                                       float* __restrict__ partial) {
    const int i = blockIdx.x * 128 + threadIdx.x;
    float s1 = 0.f, s2 = 0.f;
#pragma unroll 8
    for (int p = 0; p < NSUB; ++p) {
        s1 += RPART[(size_t)p * NU + i];
        s2 += RPART[(size_t)p * NU + NR + i];
    }
    const float e2 = 7.389056099f;  // exp(1/tau)
    float v = 0.5f * (logf(s1 - e2) + logf(s2 - e2)) - dvec[i];
#pragma unroll
    for (int m = 32; m; m >>= 1) v += __shfl_xor(v, m);
    __shared__ float wsum[2];
    if ((threadIdx.x & 63) == 0) wsum[threadIdx.x >> 6] = v;
    __syncthreads();
    if (threadIdx.x == 0) partial[blockIdx.x] = wsum[0] + wsum[1];
}

__global__ __launch_bounds__(128) void loss_final_kernel(const float* __restrict__ partial,
                                                         float* __restrict__ out, int nb) {
    float s = 0.f;
    for (int i = threadIdx.x; i < nb; i += 128) s += partial[i];
#pragma unroll
    for (int m = 32; m; m >>= 1) s += __shfl_xor(s, m);
    __shared__ float wsum[2];
    if ((threadIdx.x & 63) == 0) wsum[threadIdx.x >> 6] = s;
    __syncthreads();
    if (threadIdx.x == 0) out[0] = (wsum[0] + wsum[1]) * (1.f / (float)NR);
}

extern "C" void kernel_launch(void* const* d_in, const int* in_sizes, int n_in,
                              void* d_out, int out_size, void* d_ws, size_t ws_size,
                              hipStream_t stream) {
    const float* z1 = (const float*)d_in[0];
    const float* z2 = (const float*)d_in[1];
    const float* W1 = (const float*)d_in[2];
    const float* b1 = (const float*)d_in[3];
    const float* W2 = (const float*)d_in[4];
    const float* b2 = (const float*)d_in[5];

    char* ws = (char*)d_ws;
    size_t off = 0;
    auto alloc = [&](size_t bytes) {
        void* p = ws + off;
        off += (bytes + 255) & ~(size_t)255;
        return p;
    };
    unsigned short* W1t = (unsigned short*)alloc(HD * HD * 2);
    unsigned short* W2t = (unsigned short*)alloc(HD * HD * 2);
    unsigned char* nU = (unsigned char*)alloc((size_t)NU * HD);   // fp8, LAM-scaled
    float* dvec = (float*)alloc(NR * 4);
    float* partial = (float*)alloc(96 * 4);
    float* RPART = (float*)alloc((size_t)NSUB * NU * 4);          // 37.75 MB, fully written by gram

    transpose_cast_kernel<<<HD, 256, 0, stream>>>(W1, W1t);
    transpose_cast_kernel<<<HD, 256, 0, stream>>>(W2, W2t);

    fused_proj_kernel<<<NR / 64, 256, 0, stream>>>(z1, z2, W1t, W2t, b1, b2, nU, dvec);

    gram_kernel<<<NBLK, 256, 0, stream>>>(nU, RPART);

    loss_sum_kernel<<<NR / 128, 128, 0, stream>>>(RPART, dvec, partial);
    loss_final_kernel<<<1, 128, 0, stream>>>(partial, (float*)d_out, NR / 128);
}